// Round 6
// baseline (162.915 us; speedup 1.0000x reference)
//
#include <hip/hip_runtime.h>
#include <hip/hip_bf16.h>
#include <stdint.h>

// Problem dims
#define T_HRZ 1024
#define NBAT  128
#define NHID  256
#define NPAIR 128
#define NUIN  64
#define NYOUT 64
#define LCH   16   // chunk length
#define CCH   64   // number of chunks

// Workspace layout (float offsets). Total ~4.24M floats = 17 MB.
#define WS_LAM   0         // lr[128], li[128]
#define WS_LAML  256       // lambda^16 r[128], i[128]
#define WS_X0P   512       // x0 pair-interleaved [b][j][2]
#define WS_WBU   33280     // bf16 B-frags for Bu GEMM [nt16][kk2][lane64][j8]
#define WS_WBY   41472     // bf16 B-frags for Y GEMM  [nt4][kk8][lane64][j8]
#define WS_S     49664     // chunk sums [c][b][j] float2
#define WS_E     2146816   // entry states [c][b][j] float2

#define X16_PITCH 264      // shorts; 132 dwords, 132%32=4 -> <=2-way conflicts
#define XA_SB 136          // shorts
#define XA_SK 552          // shorts

typedef __attribute__((ext_vector_type(8))) short short8;
typedef __attribute__((ext_vector_type(4))) float float4v;

union Frag { short8 s8; unsigned int u32[4]; };

__device__ __forceinline__ unsigned int f2bf_bits(float x) {
  unsigned int u = __float_as_uint(x);
  return (u + 0x7fffu + ((u >> 16) & 1u)) >> 16;  // RNE
}

__device__ __forceinline__ unsigned int pkbf(float a, float b) {
  __hip_bfloat162 h = __float22bfloat162_rn(make_float2(a, b));
  union { __hip_bfloat162 h2; unsigned int u; } cv; cv.h2 = h; return cv.u;
}

// ---------------------------------------------------------------------------
// K1: prep. grid (NBAT+3) x 256.
// ---------------------------------------------------------------------------
__global__ __launch_bounds__(256) void k_prep(
    const float* __restrict__ y0, const float* __restrict__ lrc,
    const float* __restrict__ lic, const float* __restrict__ Bm,
    const float* __restrict__ Wy2x, const float* __restrict__ by2x,
    const float* __restrict__ Wx2y, float* __restrict__ ws)
{
  int blk = blockIdx.x;
  int h = threadIdx.x;  // 0..255
  if (blk < NBAT) {
    __shared__ float y0s[NYOUT];
    if (h < NYOUT) y0s[h] = y0[blk * NYOUT + h];
    __syncthreads();
    float acc = by2x[h];
    const float* wr = Wy2x + h * NYOUT;
#pragma unroll 16
    for (int k = 0; k < NYOUT; ++k) acc += y0s[k] * wr[k];
    int j = h & (NPAIR - 1);
    int comp = h >> 7;
    ws[WS_X0P + (blk * NPAIR + j) * 2 + comp] = acc;
  } else if (blk == NBAT) {
    if (h < NPAIR) {
      float a  = fabsf(lrc[h]);
      float r  = expf(-a);
      float th = 1.5707963267948966f * lic[h];
      float lr = r * cosf(th);
      float li = r * sinf(th);
      ws[WS_LAM + h]         = lr;
      ws[WS_LAM + NPAIR + h] = li;
      float pr = lr, pi_ = li;
      for (int l = 1; l < LCH; ++l) {
        float nr = pr * lr - pi_ * li;
        float ni = pr * li + pi_ * lr;
        pr = nr; pi_ = ni;
      }
      ws[WS_LAML + h]         = pr;  // lambda^16
      ws[WS_LAML + NPAIR + h] = pi_;
    }
  } else if (blk == NBAT + 1) {
    unsigned short* wbu = (unsigned short*)(ws + WS_WBU);
    for (int idx = h; idx < 16384; idx += 256) {
      int nt   = idx >> 10;
      int kk   = (idx >> 9) & 1;
      int lane = (idx >> 3) & 63;
      int jj   = idx & 7;
      int u  = kk * 32 + (lane >> 4) * 8 + jj;
      int hh = nt * 16 + (lane & 15);
      float a2 = fabsf(lrc[hh & (NPAIR - 1)]);
      float nf = sqrtf(1.f - expf(-2.f * a2));
      wbu[idx] = (unsigned short)f2bf_bits(Bm[hh * NUIN + u] * nf);
    }
  } else {
    unsigned short* wby = (unsigned short*)(ws + WS_WBY);
    for (int idx = h; idx < 16384; idx += 256) {
      int nt   = idx >> 12;
      int kk   = (idx >> 9) & 7;
      int lane = (idx >> 3) & 63;
      int jj   = idx & 7;
      int hh = kk * 32 + (lane >> 4) * 8 + jj;
      int y  = nt * 16 + (lane & 15);
      wby[idx] = (unsigned short)f2bf_bits(Wx2y[y * NHID + hh]);
    }
  }
}

// ---------------------------------------------------------------------------
// K2: phase A persistent. grid 512 x 256. Block = (c = bid>>3, b-slab of 16).
// 8 pipelined iterations x 2 batch-tiles: U prefetch -> Bu MFMA -> packed
// bf16 LDS transpose -> 16-step weighted scan -> S.
// ---------------------------------------------------------------------------
__global__ __launch_bounds__(256, 2) void k_phaseA(
    const float* __restrict__ U, float* __restrict__ ws)
{
  const int bid = blockIdx.x, tid = threadIdx.x;
  __shared__ unsigned short X16[2][LCH * X16_PITCH];

  const int c  = bid >> 3;
  const int b0 = (bid & 7) << 4;
  const int w = tid >> 6, lane = tid & 63;
  const int wt = w & 1;             // wave within tile
  const int tg = w >> 1;            // tile group (MFMA)
  const int l15 = lane & 15, q = lane >> 4;
  const int g = tid >> 7;           // tile group (scan)
  const int jscan = tid & 127;

  const float lr = ws[WS_LAM + jscan], li = ws[WS_LAM + NPAIR + jscan];
  const short8* wbu = (const short8*)(ws + WS_WBU);
  const float4v z = {0.f, 0.f, 0.f, 0.f};
  float2* Sp = (float2*)(ws + WS_S);

  float4 cur0, cur1, cur2, cur3, nxt0, nxt1, nxt2, nxt3;
  {
    const float* p = U + ((size_t)(c * LCH + l15) * NBAT + (b0 + tg)) * NUIN + q * 8;
    cur0 = *(const float4*)(p);      cur1 = *(const float4*)(p + 4);
    cur2 = *(const float4*)(p + 32); cur3 = *(const float4*)(p + 36);
  }
#pragma unroll
  for (int i = 0; i < 8; ++i) {
    if (i < 7) {
      const float* p = U + ((size_t)(c * LCH + l15) * NBAT + (b0 + 2 * (i + 1) + tg)) * NUIN + q * 8;
      nxt0 = *(const float4*)(p);      nxt1 = *(const float4*)(p + 4);
      nxt2 = *(const float4*)(p + 32); nxt3 = *(const float4*)(p + 36);
    }
    Frag afr[2];
    afr[0].u32[0] = pkbf(cur0.x, cur0.y); afr[0].u32[1] = pkbf(cur0.z, cur0.w);
    afr[0].u32[2] = pkbf(cur1.x, cur1.y); afr[0].u32[3] = pkbf(cur1.z, cur1.w);
    afr[1].u32[0] = pkbf(cur2.x, cur2.y); afr[1].u32[1] = pkbf(cur2.z, cur2.w);
    afr[1].u32[2] = pkbf(cur3.x, cur3.y); afr[1].u32[3] = pkbf(cur3.z, cur3.w);

    float4v acc[8];
#pragma unroll
    for (int n = 0; n < 8; ++n) acc[n] = z;
#pragma unroll
    for (int n = 0; n < 8; ++n) {
      int nt = wt * 8 + n;
      acc[n] = __builtin_amdgcn_mfma_f32_16x16x32_bf16(afr[0].s8, wbu[(nt * 2 + 0) * 64 + lane], acc[n], 0, 0, 0);
      acc[n] = __builtin_amdgcn_mfma_f32_16x16x32_bf16(afr[1].s8, wbu[(nt * 2 + 1) * 64 + lane], acc[n], 0, 0, 0);
    }
#pragma unroll
    for (int n = 0; n < 8; ++n) {
      int hh = (wt * 8 + n) * 16 + l15;
      int off = (hh & 127) * 2 + (hh >> 7);
#pragma unroll
      for (int r = 0; r < 4; ++r)
        X16[tg][(q * 4 + r) * X16_PITCH + off] = (unsigned short)f2bf_bits(acc[n][r]);
    }
    __syncthreads();

    unsigned int pk[LCH];
#pragma unroll
    for (int l = 0; l < LCH; ++l)
      pk[l] = *(const unsigned int*)(&X16[g][l * X16_PITCH + jscan * 2]);
    float s1 = 0.f, s2 = 0.f;
#pragma unroll
    for (int l = 0; l < LCH; ++l) {
      float v1 = __uint_as_float(pk[l] << 16);
      float v2 = __uint_as_float(pk[l] & 0xffff0000u);
      float n1 = lr * s1 - li * s2 + v1;
      float n2 = li * s1 + lr * s2 + v2;
      s1 = n1; s2 = n2;
    }
    int bs = b0 + 2 * i + g;
    Sp[((size_t)c * NBAT + bs) * NPAIR + jscan] = make_float2(s1, s2);
    __syncthreads();
    if (i < 7) { cur0 = nxt0; cur1 = nxt1; cur2 = nxt2; cur3 = nxt3; }
  }
}

// ---------------------------------------------------------------------------
// K3: phase B. grid NBAT x 128. 64-step chunk scan, 8-way prefetch.
// ---------------------------------------------------------------------------
__global__ __launch_bounds__(128) void k_phaseB(float* __restrict__ ws)
{
  int b = blockIdx.x, j = threadIdx.x;
  float e1 = ws[WS_X0P + (b * NPAIR + j) * 2 + 0];
  float e2 = ws[WS_X0P + (b * NPAIR + j) * 2 + 1];
  float Lr = ws[WS_LAML + j], Li = ws[WS_LAML + NPAIR + j];
  const float2* sp = (const float2*)(ws + WS_S);
  float2* ep = (float2*)(ws + WS_E);
  const size_t cs = (size_t)NBAT * NPAIR;
  size_t o0 = (size_t)b * NPAIR + j;
  float2 buf[8];
#pragma unroll
  for (int k = 0; k < 8; ++k) buf[k] = sp[k * cs + o0];
  for (int g = 0; g < 8; ++g) {
    float2 nxt[8];
    if (g < 7) {
#pragma unroll
      for (int k = 0; k < 8; ++k) nxt[k] = sp[(size_t)((g + 1) * 8 + k) * cs + o0];
    }
#pragma unroll
    for (int k = 0; k < 8; ++k) {
      ep[(size_t)(g * 8 + k) * cs + o0] = make_float2(e1, e2);
      float n1 = Lr * e1 - Li * e2 + buf[k].x;
      float n2 = Li * e1 + Lr * e2 + buf[k].y;
      e1 = n1; e2 = n2;
    }
    if (g < 7) {
#pragma unroll
      for (int k = 0; k < 8; ++k) buf[k] = nxt[k];
    }
  }
}

// ---------------------------------------------------------------------------
// K4: phase C persistent. grid 512 x 256. Same tiling as phase A; per tile:
// Bu recompute MFMA -> scan from e[c] -> padded XA -> Y-MFMA -> bias -> out.
// ---------------------------------------------------------------------------
__global__ __launch_bounds__(256, 2) void k_phaseC(
    const float* __restrict__ U, const float* __restrict__ bx2y,
    float* __restrict__ out, float* __restrict__ ws)
{
  const int bid = blockIdx.x, tid = threadIdx.x;
  __shared__ unsigned short X16[2][LCH * X16_PITCH];
  __shared__ unsigned short XA[2][8 * XA_SK];

  const int c  = bid >> 3;
  const int b0 = (bid & 7) << 4;
  const int w = tid >> 6, lane = tid & 63;
  const int wt = w & 1;
  const int tg = w >> 1;
  const int l15 = lane & 15, q = lane >> 4;
  const int g = tid >> 7;
  const int jscan = tid & 127;

  const float lr = ws[WS_LAM + jscan], li = ws[WS_LAM + NPAIR + jscan];
  const short8* wbu = (const short8*)(ws + WS_WBU);
  const short8* wby = (const short8*)(ws + WS_WBY);
  const float2* Ep = (const float2*)(ws + WS_E);
  const float4v z = {0.f, 0.f, 0.f, 0.f};
  const int nt0 = wt * 2, nt1 = nt0 + 1;
  const float bias0 = bx2y[nt0 * 16 + l15];
  const float bias1 = bx2y[nt1 * 16 + l15];
  const int base1 = (jscan >> 5) * XA_SK + ((jscan >> 3) & 3) * XA_SB + (jscan & 7);
  const int base2 = ((jscan >> 5) + 4) * XA_SK + ((jscan >> 3) & 3) * XA_SB + (jscan & 7);

  float4 cur0, cur1, cur2, cur3, nxt0, nxt1, nxt2, nxt3;
  float2 ec, en;
  {
    const float* p = U + ((size_t)(c * LCH + l15) * NBAT + (b0 + tg)) * NUIN + q * 8;
    cur0 = *(const float4*)(p);      cur1 = *(const float4*)(p + 4);
    cur2 = *(const float4*)(p + 32); cur3 = *(const float4*)(p + 36);
    ec = Ep[((size_t)c * NBAT + (b0 + g)) * NPAIR + jscan];
  }
#pragma unroll
  for (int i = 0; i < 8; ++i) {
    if (i < 7) {
      const float* p = U + ((size_t)(c * LCH + l15) * NBAT + (b0 + 2 * (i + 1) + tg)) * NUIN + q * 8;
      nxt0 = *(const float4*)(p);      nxt1 = *(const float4*)(p + 4);
      nxt2 = *(const float4*)(p + 32); nxt3 = *(const float4*)(p + 36);
      en = Ep[((size_t)c * NBAT + (b0 + 2 * (i + 1) + g)) * NPAIR + jscan];
    }
    Frag afr[2];
    afr[0].u32[0] = pkbf(cur0.x, cur0.y); afr[0].u32[1] = pkbf(cur0.z, cur0.w);
    afr[0].u32[2] = pkbf(cur1.x, cur1.y); afr[0].u32[3] = pkbf(cur1.z, cur1.w);
    afr[1].u32[0] = pkbf(cur2.x, cur2.y); afr[1].u32[1] = pkbf(cur2.z, cur2.w);
    afr[1].u32[2] = pkbf(cur3.x, cur3.y); afr[1].u32[3] = pkbf(cur3.z, cur3.w);

    float4v acc[8];
#pragma unroll
    for (int n = 0; n < 8; ++n) acc[n] = z;
#pragma unroll
    for (int n = 0; n < 8; ++n) {
      int nt = wt * 8 + n;
      acc[n] = __builtin_amdgcn_mfma_f32_16x16x32_bf16(afr[0].s8, wbu[(nt * 2 + 0) * 64 + lane], acc[n], 0, 0, 0);
      acc[n] = __builtin_amdgcn_mfma_f32_16x16x32_bf16(afr[1].s8, wbu[(nt * 2 + 1) * 64 + lane], acc[n], 0, 0, 0);
    }
#pragma unroll
    for (int n = 0; n < 8; ++n) {
      int hh = (wt * 8 + n) * 16 + l15;
      int off = (hh & 127) * 2 + (hh >> 7);
#pragma unroll
      for (int r = 0; r < 4; ++r)
        X16[tg][(q * 4 + r) * X16_PITCH + off] = (unsigned short)f2bf_bits(acc[n][r]);
    }
    __syncthreads();

    unsigned int pk[LCH];
#pragma unroll
    for (int l = 0; l < LCH; ++l)
      pk[l] = *(const unsigned int*)(&X16[g][l * X16_PITCH + jscan * 2]);
    float x1 = ec.x, x2 = ec.y;
#pragma unroll
    for (int l = 0; l < LCH; ++l) {
      float v1 = __uint_as_float(pk[l] << 16);
      float v2 = __uint_as_float(pk[l] & 0xffff0000u);
      float n1 = lr * x1 - li * x2 + v1;
      float n2 = li * x1 + lr * x2 + v2;
      x1 = n1; x2 = n2;
      XA[g][base1 + l * 8] = (unsigned short)f2bf_bits(x1);
      XA[g][base2 + l * 8] = (unsigned short)f2bf_bits(x2);
    }
    __syncthreads();

    float4v acc0 = z, acc1 = z;
#pragma unroll
    for (int kk = 0; kk < 8; ++kk) {
      short8 a = *(const short8*)(&XA[tg][kk * XA_SK + q * XA_SB + l15 * 8]);
      acc0 = __builtin_amdgcn_mfma_f32_16x16x32_bf16(a, wby[(nt0 * 8 + kk) * 64 + lane], acc0, 0, 0, 0);
      acc1 = __builtin_amdgcn_mfma_f32_16x16x32_bf16(a, wby[(nt1 * 8 + kk) * 64 + lane], acc1, 0, 0, 0);
    }
    int bm = b0 + 2 * i + tg;
#pragma unroll
    for (int r = 0; r < 4; ++r) {
      int row = q * 4 + r;
      size_t o = ((size_t)(c * LCH + row) * NBAT + bm) * NYOUT;
      out[o + nt0 * 16 + l15] = acc0[r] + bias0;
      out[o + nt1 * 16 + l15] = acc1[r] + bias1;
    }
    __syncthreads();
    if (i < 7) { cur0 = nxt0; cur1 = nxt1; cur2 = nxt2; cur3 = nxt3; ec = en; }
  }
}

// ---------------------------------------------------------------------------
extern "C" void kernel_launch(void* const* d_in, const int* in_sizes, int n_in,
                              void* d_out, int out_size, void* d_ws, size_t ws_size,
                              hipStream_t stream) {
  (void)in_sizes; (void)n_in; (void)out_size; (void)ws_size;
  const float* y0   = (const float*)d_in[0];
  const float* U    = (const float*)d_in[1];
  const float* lrc  = (const float*)d_in[2];
  const float* lic  = (const float*)d_in[3];
  const float* Bm   = (const float*)d_in[4];
  const float* Wy2x = (const float*)d_in[5];
  const float* by2x = (const float*)d_in[6];
  const float* Wx2y = (const float*)d_in[7];
  const float* bx2y = (const float*)d_in[8];
  float* out = (float*)d_out;
  float* ws  = (float*)d_ws;

  k_prep<<<dim3(NBAT + 3), 256, 0, stream>>>(y0, lrc, lic, Bm, Wy2x, by2x, Wx2y, ws);
  k_phaseA<<<dim3(512), 256, 0, stream>>>(U, ws);
  k_phaseB<<<dim3(NBAT), 128, 0, stream>>>(ws);
  k_phaseC<<<dim3(512), 256, 0, stream>>>(U, bx2y, out, ws);
}

// Round 7
// 157.912 us; speedup vs baseline: 1.0317x; 1.0317x over previous
//
#include <hip/hip_runtime.h>
#include <hip/hip_bf16.h>
#include <stdint.h>

// Problem dims
#define T_HRZ 1024
#define NBAT  128
#define NHID  256
#define NPAIR 128
#define NUIN  64
#define NYOUT 64
#define LCH   16   // chunk length
#define CCH   64   // number of chunks

// Workspace layout (float offsets).
#define WS_LAM   0         // lr[128], li[128]
#define WS_LAML  256       // lambda^16 r[128], i[128]
#define WS_X0P   512       // x0 pair-interleaved [b][j][2]
#define WS_WBU   33280     // bf16 B-frags for Bu GEMM [nt16][kk2][lane64][j8]
#define WS_WBY   41472     // bf16 B-frags for Y GEMM, K-order k=2*j+comp
#define WS_S     49664     // chunk sums [c][b][j] float2
#define WS_E     2146816   // entry states [c][b][j] float2

typedef __attribute__((ext_vector_type(8))) short short8;
typedef __attribute__((ext_vector_type(4))) float float4v;

union Frag { short8 s8; unsigned int u32[4]; };

__device__ __forceinline__ unsigned int f2bf_bits(float x) {
  unsigned int u = __float_as_uint(x);
  return (u + 0x7fffu + ((u >> 16) & 1u)) >> 16;  // RNE
}

__device__ __forceinline__ unsigned int pkbf(float a, float b) {
  __hip_bfloat162 h = __float22bfloat162_rn(make_float2(a, b));
  union { __hip_bfloat162 h2; unsigned int u; } cv; cv.h2 = h; return cv.u;
}

// ---------------------------------------------------------------------------
// K1: prep. grid (NBAT+3) x 256.
// ---------------------------------------------------------------------------
__global__ __launch_bounds__(256) void k_prep(
    const float* __restrict__ y0, const float* __restrict__ lrc,
    const float* __restrict__ lic, const float* __restrict__ Bm,
    const float* __restrict__ Wy2x, const float* __restrict__ by2x,
    const float* __restrict__ Wx2y, float* __restrict__ ws)
{
  int blk = blockIdx.x;
  int h = threadIdx.x;  // 0..255
  if (blk < NBAT) {
    __shared__ float y0s[NYOUT];
    if (h < NYOUT) y0s[h] = y0[blk * NYOUT + h];
    __syncthreads();
    float acc = by2x[h];
    const float* wr = Wy2x + h * NYOUT;
#pragma unroll 16
    for (int k = 0; k < NYOUT; ++k) acc += y0s[k] * wr[k];
    int j = h & (NPAIR - 1);
    int comp = h >> 7;
    ws[WS_X0P + (blk * NPAIR + j) * 2 + comp] = acc;
  } else if (blk == NBAT) {
    if (h < NPAIR) {
      float a  = fabsf(lrc[h]);
      float r  = expf(-a);
      float th = 1.5707963267948966f * lic[h];
      float lr = r * cosf(th);
      float li = r * sinf(th);
      ws[WS_LAM + h]         = lr;
      ws[WS_LAM + NPAIR + h] = li;
      float pr = lr, pi_ = li;
      for (int l = 1; l < LCH; ++l) {
        float nr = pr * lr - pi_ * li;
        float ni = pr * li + pi_ * lr;
        pr = nr; pi_ = ni;
      }
      ws[WS_LAML + h]         = pr;  // lambda^16
      ws[WS_LAML + NPAIR + h] = pi_;
    }
  } else if (blk == NBAT + 1) {
    unsigned short* wbu = (unsigned short*)(ws + WS_WBU);
    for (int idx = h; idx < 16384; idx += 256) {
      int nt   = idx >> 10;
      int kk   = (idx >> 9) & 1;
      int lane = (idx >> 3) & 63;
      int jj   = idx & 7;
      int u  = kk * 32 + (lane >> 4) * 8 + jj;
      int hh = nt * 16 + (lane & 15);
      float a2 = fabsf(lrc[hh & (NPAIR - 1)]);
      float nf = sqrtf(1.f - expf(-2.f * a2));
      wbu[idx] = (unsigned short)f2bf_bits(Bm[hh * NUIN + u] * nf);
    }
  } else {
    // WBY with K reordered as k = 2*j + comp  ->  h = (k>>1) + (k&1)*128
    unsigned short* wby = (unsigned short*)(ws + WS_WBY);
    for (int idx = h; idx < 16384; idx += 256) {
      int nt   = idx >> 12;
      int kk   = (idx >> 9) & 7;
      int lane = (idx >> 3) & 63;
      int jj   = idx & 7;
      int k  = kk * 32 + ((lane >> 4) & 3) * 8 + jj;
      int hh = (k >> 1) + (k & 1) * NPAIR;
      int y  = nt * 16 + (lane & 15);
      wby[idx] = (unsigned short)f2bf_bits(Wx2y[y * NHID + hh]);
    }
  }
}

// ---------------------------------------------------------------------------
// K2: phase A. grid (NBAT, CCH) x 128. ZERO LDS.
// Bu via MFMA (pair-grouped nt), 16-step scan fully in registers:
// 4-step local scan per quad + Kogge-Stone across quads via shuffles.
// ---------------------------------------------------------------------------
__global__ __launch_bounds__(128, 4) void k_phaseA(
    const float* __restrict__ U, float* __restrict__ ws)
{
  const int b = blockIdx.x, c = blockIdx.y;
  const int tid = threadIdx.x, wt = tid >> 6, lane = tid & 63;
  const int l15 = lane & 15, q = lane >> 4;

  const float* urow = U + ((size_t)(c * LCH + l15) * NBAT + b) * NUIN + q * 8;
  float4 u0 = *(const float4*)(urow);
  float4 u1 = *(const float4*)(urow + 4);
  float4 u2 = *(const float4*)(urow + 32);
  float4 u3 = *(const float4*)(urow + 36);

  float lrv[4], liv[4];
#pragma unroll
  for (int p = 0; p < 4; ++p) {
    int j = wt * 64 + p * 16 + l15;
    lrv[p] = ws[WS_LAM + j];
    liv[p] = ws[WS_LAM + NPAIR + j];
  }

  Frag afr[2];
  afr[0].u32[0] = pkbf(u0.x, u0.y); afr[0].u32[1] = pkbf(u0.z, u0.w);
  afr[0].u32[2] = pkbf(u1.x, u1.y); afr[0].u32[3] = pkbf(u1.z, u1.w);
  afr[1].u32[0] = pkbf(u2.x, u2.y); afr[1].u32[1] = pkbf(u2.z, u2.w);
  afr[1].u32[2] = pkbf(u3.x, u3.y); afr[1].u32[3] = pkbf(u3.z, u3.w);

  const short8* wbu = (const short8*)(ws + WS_WBU);
  const float4v z = {0.f, 0.f, 0.f, 0.f};
  float4v accLo[4], accHi[4];
#pragma unroll
  for (int p = 0; p < 4; ++p) { accLo[p] = z; accHi[p] = z; }
#pragma unroll
  for (int p = 0; p < 4; ++p) {
    int ntLo = wt * 4 + p, ntHi = ntLo + 8;
    accLo[p] = __builtin_amdgcn_mfma_f32_16x16x32_bf16(afr[0].s8, wbu[(ntLo * 2 + 0) * 64 + lane], accLo[p], 0, 0, 0);
    accLo[p] = __builtin_amdgcn_mfma_f32_16x16x32_bf16(afr[1].s8, wbu[(ntLo * 2 + 1) * 64 + lane], accLo[p], 0, 0, 0);
    accHi[p] = __builtin_amdgcn_mfma_f32_16x16x32_bf16(afr[0].s8, wbu[(ntHi * 2 + 0) * 64 + lane], accHi[p], 0, 0, 0);
    accHi[p] = __builtin_amdgcn_mfma_f32_16x16x32_bf16(afr[1].s8, wbu[(ntHi * 2 + 1) * 64 + lane], accHi[p], 0, 0, 0);
  }

  float2* Sp = (float2*)(ws + WS_S);
#pragma unroll
  for (int p = 0; p < 4; ++p) {
    float lr = lrv[p], li = liv[p];
    // local inclusive scan over r (t = q*4+r), zero entry
    float s1 = accLo[p][0], s2 = accHi[p][0];
#pragma unroll
    for (int r = 1; r < 4; ++r) {
      float n1 = lr * s1 - li * s2 + accLo[p][r];
      float n2 = li * s1 + lr * s2 + accHi[p][r];
      s1 = n1; s2 = n2;
    }
    // lambda^4, lambda^8
    float l2r = lr * lr - li * li,      l2i = 2.f * lr * li;
    float L4r = l2r * l2r - l2i * l2i,  L4i = 2.f * l2r * l2i;
    float L8r = L4r * L4r - L4i * L4i,  L8i = 2.f * L4r * L4i;
    // Kogge-Stone inclusive across quads
    float t1 = __shfl_up(s1, 16), t2 = __shfl_up(s2, 16);
    if (q >= 1) { float n1 = s1 + L4r * t1 - L4i * t2, n2 = s2 + L4i * t1 + L4r * t2; s1 = n1; s2 = n2; }
    t1 = __shfl_up(s1, 32); t2 = __shfl_up(s2, 32);
    if (q >= 2) { float n1 = s1 + L8r * t1 - L8i * t2, n2 = s2 + L8i * t1 + L8r * t2; s1 = n1; s2 = n2; }
    if (q == 3)
      Sp[((size_t)c * NBAT + b) * NPAIR + wt * 64 + p * 16 + l15] = make_float2(s1, s2);
  }
}

// ---------------------------------------------------------------------------
// K3: phase B. grid NBAT x 128. 64-step chunk scan, 8-way prefetch.
// ---------------------------------------------------------------------------
__global__ __launch_bounds__(128) void k_phaseB(float* __restrict__ ws)
{
  int b = blockIdx.x, j = threadIdx.x;
  float e1 = ws[WS_X0P + (b * NPAIR + j) * 2 + 0];
  float e2 = ws[WS_X0P + (b * NPAIR + j) * 2 + 1];
  float Lr = ws[WS_LAML + j], Li = ws[WS_LAML + NPAIR + j];
  const float2* sp = (const float2*)(ws + WS_S);
  float2* ep = (float2*)(ws + WS_E);
  const size_t cs = (size_t)NBAT * NPAIR;
  size_t o0 = (size_t)b * NPAIR + j;
  float2 buf[8];
#pragma unroll
  for (int k = 0; k < 8; ++k) buf[k] = sp[k * cs + o0];
  for (int g = 0; g < 8; ++g) {
    float2 nxt[8];
    if (g < 7) {
#pragma unroll
      for (int k = 0; k < 8; ++k) nxt[k] = sp[(size_t)((g + 1) * 8 + k) * cs + o0];
    }
#pragma unroll
    for (int k = 0; k < 8; ++k) {
      ep[(size_t)(g * 8 + k) * cs + o0] = make_float2(e1, e2);
      float n1 = Lr * e1 - Li * e2 + buf[k].x;
      float n2 = Li * e1 + Lr * e2 + buf[k].y;
      e1 = n1; e2 = n2;
    }
    if (g < 7) {
#pragma unroll
      for (int k = 0; k < 8; ++k) buf[k] = nxt[k];
    }
  }
}

// ---------------------------------------------------------------------------
// K4: phase C. grid (NBAT, CCH) x 128. LDS = XA only (8 KB, XOR-swizzled).
// Bu MFMA -> register scan (local + KS + exclusive prefix + lambda^q * e seed)
// -> packed b32 XA writes -> Y MFMA -> bias -> out.
// ---------------------------------------------------------------------------
__global__ __launch_bounds__(128, 3) void k_phaseC(
    const float* __restrict__ U, const float* __restrict__ bx2y,
    float* __restrict__ out, float* __restrict__ ws)
{
  const int b = blockIdx.x, c = blockIdx.y;
  const int tid = threadIdx.x, wt = tid >> 6, lane = tid & 63;
  const int l15 = lane & 15, q = lane >> 4;
  __shared__ unsigned short XAs[8 * 64 * 8];  // [kk][granule-swizzled lane][j]

  const float* urow = U + ((size_t)(c * LCH + l15) * NBAT + b) * NUIN + q * 8;
  float4 u0 = *(const float4*)(urow);
  float4 u1 = *(const float4*)(urow + 4);
  float4 u2 = *(const float4*)(urow + 32);
  float4 u3 = *(const float4*)(urow + 36);

  const float2* Ep = (const float2*)(ws + WS_E);
  float lrv[4], liv[4]; float2 ev[4];
#pragma unroll
  for (int p = 0; p < 4; ++p) {
    int j = wt * 64 + p * 16 + l15;
    lrv[p] = ws[WS_LAM + j];
    liv[p] = ws[WS_LAM + NPAIR + j];
    ev[p]  = Ep[((size_t)c * NBAT + b) * NPAIR + j];
  }

  Frag afr[2];
  afr[0].u32[0] = pkbf(u0.x, u0.y); afr[0].u32[1] = pkbf(u0.z, u0.w);
  afr[0].u32[2] = pkbf(u1.x, u1.y); afr[0].u32[3] = pkbf(u1.z, u1.w);
  afr[1].u32[0] = pkbf(u2.x, u2.y); afr[1].u32[1] = pkbf(u2.z, u2.w);
  afr[1].u32[2] = pkbf(u3.x, u3.y); afr[1].u32[3] = pkbf(u3.z, u3.w);

  const short8* wbu = (const short8*)(ws + WS_WBU);
  const float4v z = {0.f, 0.f, 0.f, 0.f};
  float4v accLo[4], accHi[4];
#pragma unroll
  for (int p = 0; p < 4; ++p) { accLo[p] = z; accHi[p] = z; }
#pragma unroll
  for (int p = 0; p < 4; ++p) {
    int ntLo = wt * 4 + p, ntHi = ntLo + 8;
    accLo[p] = __builtin_amdgcn_mfma_f32_16x16x32_bf16(afr[0].s8, wbu[(ntLo * 2 + 0) * 64 + lane], accLo[p], 0, 0, 0);
    accLo[p] = __builtin_amdgcn_mfma_f32_16x16x32_bf16(afr[1].s8, wbu[(ntLo * 2 + 1) * 64 + lane], accLo[p], 0, 0, 0);
    accHi[p] = __builtin_amdgcn_mfma_f32_16x16x32_bf16(afr[0].s8, wbu[(ntHi * 2 + 0) * 64 + lane], accHi[p], 0, 0, 0);
    accHi[p] = __builtin_amdgcn_mfma_f32_16x16x32_bf16(afr[1].s8, wbu[(ntHi * 2 + 1) * 64 + lane], accHi[p], 0, 0, 0);
  }

#pragma unroll
  for (int p = 0; p < 4; ++p) {
    float lr = lrv[p], li = liv[p];
    // local inclusive prefix from zero, kept per r
    float s1 = 0.f, s2 = 0.f;
#pragma unroll
    for (int r = 0; r < 4; ++r) {
      float n1 = lr * s1 - li * s2 + accLo[p][r];
      float n2 = li * s1 + lr * s2 + accHi[p][r];
      s1 = n1; s2 = n2;
      accLo[p][r] = s1; accHi[p][r] = s2;   // L[r]
    }
    float l2r = lr * lr - li * li,      l2i = 2.f * lr * li;
    float L4r = l2r * l2r - l2i * l2i,  L4i = 2.f * l2r * l2i;
    float L8r = L4r * L4r - L4i * L4i,  L8i = 2.f * L4r * L4i;
    // KS inclusive over quad totals
    float t1 = __shfl_up(s1, 16), t2 = __shfl_up(s2, 16);
    if (q >= 1) { float n1 = s1 + L4r * t1 - L4i * t2, n2 = s2 + L4i * t1 + L4r * t2; s1 = n1; s2 = n2; }
    t1 = __shfl_up(s1, 32); t2 = __shfl_up(s2, 32);
    if (q >= 2) { float n1 = s1 + L8r * t1 - L8i * t2, n2 = s2 + L8i * t1 + L8r * t2; s1 = n1; s2 = n2; }
    // exclusive prefix P_q
    float P1 = __shfl_up(s1, 16), P2 = __shfl_up(s2, 16);
    if (q == 0) { P1 = 0.f; P2 = 0.f; }
    // lambda^{4q} * e
    float e1 = ev[p].x, e2 = ev[p].y;
    if (q & 1) { float n1 = L4r * e1 - L4i * e2, n2 = L4i * e1 + L4r * e2; e1 = n1; e2 = n2; }
    if (q & 2) { float n1 = L8r * e1 - L8i * e2, n2 = L8i * e1 + L8r * e2; e1 = n1; e2 = n2; }
    float T1 = P1 + e1, T2 = P2 + e2;
    // x[r] = L[r] + lambda^{r+1} * T ; write packed pair to XA
    float m1 = lr * T1 - li * T2, m2 = li * T1 + lr * T2;
    int kk = wt * 4 + p;
    int laneBase = (l15 >> 2) * 16 + q * 4;
    int jj = (l15 & 3) * 2;
#pragma unroll
    for (int r = 0; r < 4; ++r) {
      float x1 = accLo[p][r] + m1;
      float x2 = accHi[p][r] + m2;
      int lp = laneBase + r;
      int g  = kk * 64 + lp;
      int addr = ((g ^ (lp >> 3)) << 3) + jj;
      *(unsigned int*)(&XAs[addr]) = f2bf_bits(x1) | (f2bf_bits(x2) << 16);
      if (r < 3) { float n1 = lr * m1 - li * m2; m2 = li * m1 + lr * m2; m1 = n1; }
    }
  }
  __syncthreads();

  // Y = X @ W_x2y^T via MFMA (K-order k = 2j+comp, matches WBY)
  const short8* wby = (const short8*)(ws + WS_WBY);
  float4v acc0 = z, acc1 = z;
  const int nt0 = wt * 2, nt1 = nt0 + 1;
#pragma unroll
  for (int kk = 0; kk < 8; ++kk) {
    int g = kk * 64 + lane;
    short8 a = *(const short8*)(&XAs[(size_t)((g ^ (lane >> 3)) << 3)]);
    acc0 = __builtin_amdgcn_mfma_f32_16x16x32_bf16(a, wby[(nt0 * 8 + kk) * 64 + lane], acc0, 0, 0, 0);
    acc1 = __builtin_amdgcn_mfma_f32_16x16x32_bf16(a, wby[(nt1 * 8 + kk) * 64 + lane], acc1, 0, 0, 0);
  }

  float bias0 = bx2y[nt0 * 16 + l15];
  float bias1 = bx2y[nt1 * 16 + l15];
#pragma unroll
  for (int r = 0; r < 4; ++r) {
    int row = q * 4 + r;  // t within chunk
    size_t o = ((size_t)(c * LCH + row) * NBAT + b) * NYOUT;
    out[o + nt0 * 16 + l15] = acc0[r] + bias0;
    out[o + nt1 * 16 + l15] = acc1[r] + bias1;
  }
}

// ---------------------------------------------------------------------------
extern "C" void kernel_launch(void* const* d_in, const int* in_sizes, int n_in,
                              void* d_out, int out_size, void* d_ws, size_t ws_size,
                              hipStream_t stream) {
  (void)in_sizes; (void)n_in; (void)out_size; (void)ws_size;
  const float* y0   = (const float*)d_in[0];
  const float* U    = (const float*)d_in[1];
  const float* lrc  = (const float*)d_in[2];
  const float* lic  = (const float*)d_in[3];
  const float* Bm   = (const float*)d_in[4];
  const float* Wy2x = (const float*)d_in[5];
  const float* by2x = (const float*)d_in[6];
  const float* Wx2y = (const float*)d_in[7];
  const float* bx2y = (const float*)d_in[8];
  float* out = (float*)d_out;
  float* ws  = (float*)d_ws;

  k_prep<<<dim3(NBAT + 3), 256, 0, stream>>>(y0, lrc, lic, Bm, Wy2x, by2x, Wx2y, ws);
  k_phaseA<<<dim3(NBAT, CCH), 128, 0, stream>>>(U, ws);
  k_phaseB<<<dim3(NBAT), 128, 0, stream>>>(ws);
  k_phaseC<<<dim3(NBAT, CCH), 128, 0, stream>>>(U, bx2y, out, ws);
}